// Round 4
// baseline (562.406 us; speedup 1.0000x reference)
//
#include <hip/hip_runtime.h>
#include <hip/hip_cooperative_groups.h>
#include <math.h>

namespace cg = cooperative_groups;

#define N_NODES 50000
#define N_EDGES 400000
#define PAD 64          // padded CSR stride; Poisson(mean 8) => P(deg>64) ~ 1e-35
#define TILES1 782      // gemm1: 2 col-blocks x 391 row-blocks
#define TILES2 391      // gemm2: 1 col-block  x 391 row-blocks
#define NG1 12500       // agg1 node groups (4 nodes/block)
#define NG2 6250        // agg2 node groups (8 nodes/block)

typedef __attribute__((ext_vector_type(8))) short bf16x8;
typedef __attribute__((ext_vector_type(4))) float f32x4;

__device__ __forceinline__ float lrelu(float x){ return x > 0.f ? x : 0.2f*x; }
__device__ __forceinline__ float bf2f(unsigned short u){ return __uint_as_float(((unsigned int)u)<<16); }
__device__ __forceinline__ unsigned short f2bf(float f){
    unsigned int b = __float_as_uint(f);
    return (unsigned short)((b + 0x7FFFu + ((b>>16)&1u)) >> 16);   // RNE
}
__device__ __forceinline__ float4 bf4(ushort4 u){
    return make_float4(bf2f(u.x), bf2f(u.y), bf2f(u.z), bf2f(u.w));
}
// softmax without max-subtraction: logits are O(sigma~4); exp overflow needs ~88.
__device__ __forceinline__ float wexp(float e){ return __expf(fminf(e, 80.f)); }

// ---------------- GEMM tile (device fn): C[128x128] tile = A @ BT^T + fused att logits ----
// MODE 1 (conv1): bx == head; atomicAdd logits. MODE 2: direct store (wx = group).
template<int MODE>
__device__ void gemm_tile(unsigned short* As, unsigned short* Bs,
        const unsigned short* __restrict__ A, const unsigned short* __restrict__ BT,
        unsigned short* __restrict__ C, int M, int K, int ldc, int bx, int by,
        const float* __restrict__ attS0, const float* __restrict__ attD0,
        const float* __restrict__ attS1, const float* __restrict__ attD1,
        float* __restrict__ outS, float* __restrict__ outD){
    int t = threadIdx.x;
    int lane = t & 63, wid = t >> 6;
    int wy = wid >> 1, wx = wid & 1;
    int quad = lane >> 4, l15 = lane & 15;
    int row0 = by * 128;
    int col0 = bx * 128;

    f32x4 acc[4][4];
    #pragma unroll
    for (int i = 0; i < 4; i++)
        #pragma unroll
        for (int j = 0; j < 4; j++)
            acc[i][j] = (f32x4){0.f, 0.f, 0.f, 0.f};

    int r = t >> 2;              // 0..63
    int cofs = (t & 3) * 8;      // elem offset in k-slice

    for (int k0 = 0; k0 < K; k0 += 32){
        int gr0 = min(row0 + r,      M-1);
        int gr1 = min(row0 + r + 64, M-1);
        float4 av0 = *(const float4*)(A  + (size_t)gr0*K + k0 + cofs);
        float4 av1 = *(const float4*)(A  + (size_t)gr1*K + k0 + cofs);
        float4 bv0 = *(const float4*)(BT + (size_t)(col0 + r)*K      + k0 + cofs);
        float4 bv1 = *(const float4*)(BT + (size_t)(col0 + r + 64)*K + k0 + cofs);
        __syncthreads();
        *(float4*)&As[r*40 + cofs]      = av0;
        *(float4*)&As[(r+64)*40 + cofs] = av1;
        *(float4*)&Bs[r*40 + cofs]      = bv0;
        *(float4*)&Bs[(r+64)*40 + cofs] = bv1;
        __syncthreads();

        bf16x8 af[4], bf[4];
        #pragma unroll
        for (int i = 0; i < 4; i++)
            af[i] = *(const bf16x8*)&As[(wy*64 + i*16 + l15)*40 + quad*8];
        #pragma unroll
        for (int j = 0; j < 4; j++)
            bf[j] = *(const bf16x8*)&Bs[(wx*64 + j*16 + l15)*40 + quad*8];
        #pragma unroll
        for (int i = 0; i < 4; i++)
            #pragma unroll
            for (int j = 0; j < 4; j++)
                acc[i][j] = __builtin_amdgcn_mfma_f32_16x16x32_bf16(af[i], bf[j], acc[i][j], 0, 0, 0);
    }

    int head = bx;                           // MODE 1 only
    float aS[4], aD[4];
    #pragma unroll
    for (int j = 0; j < 4; j++){
        if (MODE == 1){
            int ch = wx*64 + j*16 + l15;
            aS[j] = attS0[head*128 + ch];
            aD[j] = attD0[head*128 + ch];
        } else {
            int c2 = j*16 + l15;
            aS[j] = wx ? attS1[c2] : attS0[c2];
            aD[j] = wx ? attD1[c2] : attD0[c2];
        }
    }

    // epilogue: C/D layout col=lane&15, row=quad*4+reg  [m89-verified]
    #pragma unroll
    for (int i = 0; i < 4; i++){
        #pragma unroll
        for (int reg = 0; reg < 4; reg++){
            int rr = row0 + wy*64 + i*16 + quad*4 + reg;
            float sp = 0.f, dp = 0.f;
            #pragma unroll
            for (int j = 0; j < 4; j++){
                float v = acc[i][j][reg];
                int cc = col0 + wx*64 + j*16 + l15;
                if (rr < M) C[(size_t)rr*ldc + cc] = f2bf(v);
                sp = fmaf(v, aS[j], sp);
                dp = fmaf(v, aD[j], dp);
            }
            #pragma unroll
            for (int msk = 1; msk < 16; msk <<= 1){
                sp += __shfl_xor(sp, msk);
                dp += __shfl_xor(dp, msk);
            }
            if (l15 == 0 && rr < M){
                if (MODE == 1){
                    atomicAdd(&outS[rr*2 + head], sp);
                    atomicAdd(&outD[rr*2 + head], dp);
                } else {
                    outS[rr*2 + wx] = sp;
                    outD[rr*2 + wx] = dp;
                }
            }
        }
    }
}

// ---------------- single cooperative kernel: prep -> gemm1 -> agg1 -> gemm2 -> agg2 ----
__global__ __launch_bounds__(256, 4) void fused_k(
        const float* __restrict__ x, const int* __restrict__ src, const int* __restrict__ dst,
        const float* __restrict__ W1, const float* __restrict__ attS1v, const float* __restrict__ attD1v,
        const float* __restrict__ b1,
        const float* __restrict__ Wmu, const float* __restrict__ attSmu, const float* __restrict__ attDmu,
        const float* __restrict__ bmu,
        const float* __restrict__ Wls, const float* __restrict__ attSls, const float* __restrict__ attDls,
        const float* __restrict__ bls,
        unsigned short* __restrict__ xb, unsigned short* __restrict__ h1,
        unsigned short* __restrict__ hbuf, unsigned short* __restrict__ hml,
        unsigned short* __restrict__ W1T, unsigned short* __restrict__ WmlT,
        int* __restrict__ counts, int* __restrict__ csr,
        float* __restrict__ as1, float* __restrict__ ad1,
        float* __restrict__ as2, float* __restrict__ ad2,
        float* __restrict__ out)
{
    __shared__ unsigned short As[128*40];
    __shared__ unsigned short Bs[128*40];
    cg::grid_group grid = cg::this_grid();
    const int tid = threadIdx.x, bid = blockIdx.x, nb = gridDim.x;
    const int gthr = bid*256 + tid, gsz = nb*256;

    // ---- P0: prep (x cast, W transpose+cast, padded-CSR scatter) ----
    for (int i = gthr; i < (N_NODES*128)/4; i += gsz){
        float4 v = ((const float4*)x)[i];
        ((ushort4*)xb)[i] = make_ushort4(f2bf(v.x), f2bf(v.y), f2bf(v.z), f2bf(v.w));
    }
    for (int i = gthr; i < 32768; i += gsz){
        int n = i >> 7, k = i & 127;
        W1T[i] = f2bf(W1[k*256 + n]);                 // W1T[n][k] = W1[k][n] (256x128)
        int n2 = i >> 8, k2 = i & 255;
        float v = (n2 < 64) ? Wmu[k2*64 + n2] : Wls[k2*64 + (n2-64)];
        WmlT[i] = f2bf(v);                            // WmlT[n][k] (128x256)
    }
    for (int e = gthr; e < N_EDGES; e += gsz){
        int d = dst[e];
        int pos = atomicAdd(&counts[d], 1);           // counts doubles as degree array
        csr[d*PAD + pos] = src[e];
    }
    grid.sync();

    // ---- P1: gemm1  h1[N,256] = xb @ W1T^T (+ fused att1 logits via atomics) ----
    for (int t = bid; t < TILES1; t += nb)
        gemm_tile<1>(As, Bs, xb, W1T, h1, N_NODES, 128, 256, t & 1, t >> 1,
                     attS1v, attD1v, nullptr, nullptr, as1, ad1);
    grid.sync();

    // ---- P2: agg1 (R1-proven body: branch-free softmax, unroll-4) ----
    for (int g = bid; g < NG1; g += nb){
        int wave = tid >> 6, lane = tid & 63;
        int n = g*4 + wave;
        int head = lane >> 5;
        const ushort4* h1v = (const ushort4*)h1;
        const float2* asv = (const float2*)as1;

        float2 adn = ((const float2*)ad1)[n], asn = asv[n];
        float adh = head ? adn.y : adn.x;
        float ash = head ? asn.y : asn.x;

        float w = wexp(lrelu(ash + adh));             // self-loop
        float l = w;
        float4 r = bf4(h1v[(size_t)n*64 + lane]);
        float4 acc = make_float4(w*r.x, w*r.y, w*r.z, w*r.w);

        int deg = counts[n];
        int off = n*PAD;
        int dm1 = deg - 1;
        for (int k = 0; k < deg; k += 4){
            int s0 = csr[off + k];
            int s1 = csr[off + min(k+1, dm1)];
            int s2 = csr[off + min(k+2, dm1)];
            int s3 = csr[off + min(k+3, dm1)];
            float2 a0 = asv[s0], a1 = asv[s1], a2 = asv[s2], a3 = asv[s3];
            float4 r0 = bf4(h1v[(size_t)s0*64 + lane]);
            float4 r1 = bf4(h1v[(size_t)s1*64 + lane]);
            float4 r2 = bf4(h1v[(size_t)s2*64 + lane]);
            float4 r3 = bf4(h1v[(size_t)s3*64 + lane]);
            float w0 = wexp(lrelu((head ? a0.y : a0.x) + adh));
            float w1 = (k+1 <= dm1) ? wexp(lrelu((head ? a1.y : a1.x) + adh)) : 0.f;
            float w2 = (k+2 <= dm1) ? wexp(lrelu((head ? a2.y : a2.x) + adh)) : 0.f;
            float w3 = (k+3 <= dm1) ? wexp(lrelu((head ? a3.y : a3.x) + adh)) : 0.f;
            l += (w0 + w1) + (w2 + w3);
            acc.x = fmaf(w0, r0.x, acc.x); acc.x = fmaf(w1, r1.x, acc.x);
            acc.x = fmaf(w2, r2.x, acc.x); acc.x = fmaf(w3, r3.x, acc.x);
            acc.y = fmaf(w0, r0.y, acc.y); acc.y = fmaf(w1, r1.y, acc.y);
            acc.y = fmaf(w2, r2.y, acc.y); acc.y = fmaf(w3, r3.y, acc.y);
            acc.z = fmaf(w0, r0.z, acc.z); acc.z = fmaf(w1, r1.z, acc.z);
            acc.z = fmaf(w2, r2.z, acc.z); acc.z = fmaf(w3, r3.z, acc.z);
            acc.w = fmaf(w0, r0.w, acc.w); acc.w = fmaf(w1, r1.w, acc.w);
            acc.w = fmaf(w2, r2.w, acc.w); acc.w = fmaf(w3, r3.w, acc.w);
        }

        float invl = 1.f / (l + 1e-16f);
        float4 b4 = *(const float4*)&b1[lane*4];
        float4 v;
        v.x = acc.x*invl + b4.x; v.y = acc.y*invl + b4.y;
        v.z = acc.z*invl + b4.z; v.w = acc.w*invl + b4.w;
        v.x = v.x > 0.f ? v.x : __expf(v.x) - 1.f;    // ELU
        v.y = v.y > 0.f ? v.y : __expf(v.y) - 1.f;
        v.z = v.z > 0.f ? v.z : __expf(v.z) - 1.f;
        v.w = v.w > 0.f ? v.w : __expf(v.w) - 1.f;
        ((ushort4*)hbuf)[(size_t)n*64 + lane] = make_ushort4(f2bf(v.x), f2bf(v.y), f2bf(v.z), f2bf(v.w));
    }
    grid.sync();

    // ---- P3: gemm2  hml[N,128] = hbuf @ WmlT^T (+ fused att2 logits, direct store) ----
    for (int t = bid; t < TILES2; t += nb)
        gemm_tile<2>(As, Bs, hbuf, WmlT, hml, N_NODES, 256, 128, 0, t,
                     attSmu, attDmu, attSls, attDls, as2, ad2);
    grid.sync();

    // ---- P4: agg2 (R1-proven body) ----
    for (int g = bid; g < NG2; g += nb){
        int grp = tid >> 5, lane = tid & 31;
        int n = g*8 + grp;
        int gg = lane >> 4;                           // 0 = mu, 1 = ls
        const ushort4* hv = (const ushort4*)hml;
        const float2* asv = (const float2*)as2;

        float2 adn = ((const float2*)ad2)[n], asn = asv[n];
        float adh = gg ? adn.y : adn.x;
        float ash = gg ? asn.y : asn.x;

        float w = wexp(lrelu(ash + adh));             // self-loop
        float l = w;
        float4 r = bf4(hv[(size_t)n*32 + lane]);
        float4 acc = make_float4(w*r.x, w*r.y, w*r.z, w*r.w);

        int deg = counts[n];
        int off = n*PAD;
        int dm1 = deg - 1;
        for (int k = 0; k < deg; k += 4){
            int s0 = csr[off + k];
            int s1 = csr[off + min(k+1, dm1)];
            int s2 = csr[off + min(k+2, dm1)];
            int s3 = csr[off + min(k+3, dm1)];
            float2 a0 = asv[s0], a1 = asv[s1], a2 = asv[s2], a3 = asv[s3];
            float4 r0 = bf4(hv[(size_t)s0*32 + lane]);
            float4 r1 = bf4(hv[(size_t)s1*32 + lane]);
            float4 r2 = bf4(hv[(size_t)s2*32 + lane]);
            float4 r3 = bf4(hv[(size_t)s3*32 + lane]);
            float w0 = wexp(lrelu((gg ? a0.y : a0.x) + adh));
            float w1 = (k+1 <= dm1) ? wexp(lrelu((gg ? a1.y : a1.x) + adh)) : 0.f;
            float w2 = (k+2 <= dm1) ? wexp(lrelu((gg ? a2.y : a2.x) + adh)) : 0.f;
            float w3 = (k+3 <= dm1) ? wexp(lrelu((gg ? a3.y : a3.x) + adh)) : 0.f;
            l += (w0 + w1) + (w2 + w3);
            acc.x = fmaf(w0, r0.x, acc.x); acc.x = fmaf(w1, r1.x, acc.x);
            acc.x = fmaf(w2, r2.x, acc.x); acc.x = fmaf(w3, r3.x, acc.x);
            acc.y = fmaf(w0, r0.y, acc.y); acc.y = fmaf(w1, r1.y, acc.y);
            acc.y = fmaf(w2, r2.y, acc.y); acc.y = fmaf(w3, r3.y, acc.y);
            acc.z = fmaf(w0, r0.z, acc.z); acc.z = fmaf(w1, r1.z, acc.z);
            acc.z = fmaf(w2, r2.z, acc.z); acc.z = fmaf(w3, r3.z, acc.z);
            acc.w = fmaf(w0, r0.w, acc.w); acc.w = fmaf(w1, r1.w, acc.w);
            acc.w = fmaf(w2, r2.w, acc.w); acc.w = fmaf(w3, r3.w, acc.w);
        }

        float invl = 1.f / (l + 1e-16f);
        int c = (lane & 15) * 4;
        const float* bb = gg ? bls : bmu;
        float4 b4 = *(const float4*)&bb[c];
        float4 v;
        v.x = acc.x*invl + b4.x; v.y = acc.y*invl + b4.y;
        v.z = acc.z*invl + b4.z; v.w = acc.w*invl + b4.w;
        float* base = gg ? (out + (size_t)N_NODES*64) : out;
        *(float4*)&base[(size_t)n*64 + c] = v;
    }
}

extern "C" void kernel_launch(void* const* d_in, const int* in_sizes, int n_in,
                              void* d_out, int out_size, void* d_ws, size_t ws_size,
                              hipStream_t stream) {
    const float* x           = (const float*)d_in[0];
    const int*   ei          = (const int*)d_in[1];
    const float* W1          = (const float*)d_in[2];
    const float* att_src1    = (const float*)d_in[3];
    const float* att_dst1    = (const float*)d_in[4];
    const float* b1          = (const float*)d_in[5];
    const float* W_mu        = (const float*)d_in[6];
    const float* att_src_mu  = (const float*)d_in[7];
    const float* att_dst_mu  = (const float*)d_in[8];
    const float* b_mu        = (const float*)d_in[9];
    const float* W_ls        = (const float*)d_in[10];
    const float* att_src_ls  = (const float*)d_in[11];
    const float* att_dst_ls  = (const float*)d_in[12];
    const float* b_ls        = (const float*)d_in[13];
    float* out = (float*)d_out;

    const int* srcp = ei;
    const int* dstp = ei + N_EDGES;

    // workspace layout (bf16 stored as unsigned short)
    unsigned short* xb   = (unsigned short*)d_ws;            // [N,128]
    unsigned short* h1   = xb   + (size_t)N_NODES*128;       // [N,256]
    unsigned short* hbuf = h1   + (size_t)N_NODES*256;       // [N,256] post-ELU
    unsigned short* hml  = hbuf + (size_t)N_NODES*256;       // [N,128] = [hm|hl]
    unsigned short* W1T  = hml  + (size_t)N_NODES*128;       // [256,128]
    unsigned short* WmlT = W1T  + 32768;                     // [128,256]
    int*   counts = (int*)(WmlT + 32768);                    // [N]  (zeroed)
    float* as1    = (float*)(counts + N_NODES);              // [N,2] (zeroed, atomics)
    float* ad1    = as1 + 2*N_NODES;                         // [N,2] (zeroed, atomics)
    float* as2    = ad1 + 2*N_NODES;                         // [N,2]
    float* ad2    = as2 + 2*N_NODES;                         // [N,2]
    int*   csr    = (int*)(ad2 + 2*N_NODES);                 // [N,PAD]

    // one memset covers counts + as1 + ad1 (contiguous); as2/ad2 written directly
    hipMemsetAsync(counts, 0, N_NODES*sizeof(int) + 4*N_NODES*sizeof(float), stream);

    // resident-grid size for cooperative launch (grid-stride phases accept any size)
    int occ = 0;
    if (hipOccupancyMaxActiveBlocksPerMultiprocessor(&occ, (const void*)fused_k, 256, 0) != hipSuccess || occ < 1)
        occ = 1;
    int grid = occ * 256;
    if (grid > 1024) grid = 1024;

    void* args[] = {
        (void*)&x, (void*)&srcp, (void*)&dstp,
        (void*)&W1, (void*)&att_src1, (void*)&att_dst1, (void*)&b1,
        (void*)&W_mu, (void*)&att_src_mu, (void*)&att_dst_mu, (void*)&b_mu,
        (void*)&W_ls, (void*)&att_src_ls, (void*)&att_dst_ls, (void*)&b_ls,
        (void*)&xb, (void*)&h1, (void*)&hbuf, (void*)&hml,
        (void*)&W1T, (void*)&WmlT,
        (void*)&counts, (void*)&csr,
        (void*)&as1, (void*)&ad1, (void*)&as2, (void*)&ad2,
        (void*)&out
    };
    hipLaunchCooperativeKernel((const void*)fused_k, dim3(grid), dim3(256), args, 0, stream);
}

// Round 5
// 231.396 us; speedup vs baseline: 2.4305x; 2.4305x over previous
//
#include <hip/hip_runtime.h>
#include <math.h>

#define N_NODES 50000
#define N_EDGES 400000
#define PAD 64          // padded CSR stride; Poisson(mean 8) => P(deg>64) ~ 1e-35

typedef __attribute__((ext_vector_type(8))) short bf16x8;
typedef __attribute__((ext_vector_type(4))) float f32x4;

__device__ __forceinline__ float lrelu(float x){ return x > 0.f ? x : 0.2f*x; }
__device__ __forceinline__ float bf2f(unsigned short u){ return __uint_as_float(((unsigned int)u)<<16); }
__device__ __forceinline__ unsigned short f2bf(float f){
    unsigned int b = __float_as_uint(f);
    return (unsigned short)((b + 0x7FFFu + ((b>>16)&1u)) >> 16);   // RNE
}
__device__ __forceinline__ float4 bf4(ushort4 u){
    return make_float4(bf2f(u.x), bf2f(u.y), bf2f(u.z), bf2f(u.w));
}
// softmax without max-subtraction: logits are O(sigma~4); exp overflow needs ~88.
__device__ __forceinline__ float wexp(float e){ return __expf(fminf(e, 80.f)); }

// ---------------- V1 precompute: V1[v][k] = sum_c W1[k, h*128+c] * att[h,c] ----------
// v: 0=src h0, 1=src h1, 2=dst h0, 3=dst h1.  One block, 256 threads, 2 entries each.
__global__ __launch_bounds__(256) void vprep_k(const float* __restrict__ W1,
        const float* __restrict__ attS, const float* __restrict__ attD,
        float* __restrict__ V1){
    int t = threadIdx.x;
    for (int idx = t; idx < 512; idx += 256){
        int v = idx >> 7, k = idx & 127;
        int h = v & 1;
        const float* attp = (v >> 1) ? attD : attS;
        float s = 0.f;
        #pragma unroll 8
        for (int c = 0; c < 128; c++)
            s = fmaf(W1[k*256 + h*128 + c], attp[h*128 + c], s);
        V1[idx] = s;
    }
}

// ---------------- prep: row-wise x cast + logits1, W transpose+cast, CSR scatter ------
// grid = 12500 blocks x 256. Row section: 4 nodes/block, wave/node, lane owns 2 ch.
__global__ __launch_bounds__(256) void prep_k(const float* __restrict__ x, unsigned short* __restrict__ xb,
        const float* __restrict__ V1, float2* __restrict__ as1, float2* __restrict__ ad1,
        const float* __restrict__ W1, const float* __restrict__ Wmu, const float* __restrict__ Wls,
        unsigned short* __restrict__ W1T, unsigned short* __restrict__ WmlT,
        const int* __restrict__ src, const int* __restrict__ dst,
        int* __restrict__ counts, int* __restrict__ csr_src){
    int t = threadIdx.x;
    int gthr = blockIdx.x*256 + t;

    // x cast + logits1 (f32 x dot V1, full-precision)
    int n = blockIdx.x*4 + (t >> 6);
    int lane = t & 63;
    if (n < N_NODES){
        int c0 = lane*2;
        float2 xv = ((const float2*)(x + (size_t)n*128))[lane];
        ((ushort2*)(xb + (size_t)n*128))[lane] = make_ushort2(f2bf(xv.x), f2bf(xv.y));
        float s0 = xv.x*V1[      c0] + xv.y*V1[      c0+1];
        float s1 = xv.x*V1[128 + c0] + xv.y*V1[128 + c0+1];
        float d0 = xv.x*V1[256 + c0] + xv.y*V1[256 + c0+1];
        float d1 = xv.x*V1[384 + c0] + xv.y*V1[384 + c0+1];
        #pragma unroll
        for (int m = 1; m < 64; m <<= 1){
            s0 += __shfl_xor(s0, m);
            s1 += __shfl_xor(s1, m);
            d0 += __shfl_xor(d0, m);
            d1 += __shfl_xor(d1, m);
        }
        if (lane == 0){
            as1[n] = make_float2(s0, s1);
            ad1[n] = make_float2(d0, d1);
        }
    }

    // weight transpose+cast
    if (gthr < 32768){
        int i = gthr;
        int nn = i >> 7, k = i & 127;
        W1T[i] = f2bf(W1[k*256 + nn]);                // W1T[n][k] = W1[k][n] (256x128)
        int n2 = i >> 8, k2 = i & 255;
        float v = (n2 < 64) ? Wmu[k2*64 + n2] : Wls[k2*64 + (n2-64)];
        WmlT[i] = f2bf(v);                            // WmlT[n][k] (128x256)
    }

    // padded-CSR scatter
    if (gthr < N_EDGES){
        int d = dst[gthr];
        int pos = atomicAdd(&counts[d], 1);           // counts doubles as degree array
        csr_src[d*PAD + pos] = src[gthr];
    }
}

// ---------------- layer-1 aggregation in x-space: 256B rows, both heads one pass -----
// one wave per node; lane owns 2 channels (ushort2); dual accumulators (head 0/1).
__global__ __launch_bounds__(256) void agg1x_k(const unsigned short* __restrict__ xb,
        const float2* __restrict__ as, const float2* __restrict__ ad,
        const int* __restrict__ counts, const int* __restrict__ csr_src,
        unsigned short* __restrict__ aggx0, unsigned short* __restrict__ aggx1){
    int wave = threadIdx.x >> 6, lane = threadIdx.x & 63;
    int n = blockIdx.x*4 + wave;
    if (n >= N_NODES) return;

    float2 adn = ad[n], asn = as[n];
    float w0s = wexp(lrelu(asn.x + adn.x));           // self-loop, head 0
    float w1s = wexp(lrelu(asn.y + adn.y));           // self-loop, head 1
    float l0 = w0s, l1 = w1s;

    ushort2 u = ((const ushort2*)(xb + (size_t)n*128))[lane];
    float rx = bf2f(u.x), ry = bf2f(u.y);
    float a0x = w0s*rx, a0y = w0s*ry;                 // head-0 accumulator
    float a1x = w1s*rx, a1y = w1s*ry;                 // head-1 accumulator

    int deg = counts[n];
    int off = n*PAD;
    int dm1 = deg - 1;
    for (int k = 0; k < deg; k += 4){
        int s0 = csr_src[off + k];
        int s1 = csr_src[off + min(k+1, dm1)];
        int s2 = csr_src[off + min(k+2, dm1)];
        int s3 = csr_src[off + min(k+3, dm1)];
        float2 e0 = as[s0], e1 = as[s1], e2 = as[s2], e3 = as[s3];
        ushort2 u0 = ((const ushort2*)(xb + (size_t)s0*128))[lane];
        ushort2 u1 = ((const ushort2*)(xb + (size_t)s1*128))[lane];
        ushort2 u2 = ((const ushort2*)(xb + (size_t)s2*128))[lane];
        ushort2 u3 = ((const ushort2*)(xb + (size_t)s3*128))[lane];
        float w00 = wexp(lrelu(e0.x + adn.x));
        float w01 = wexp(lrelu(e0.y + adn.y));
        float w10 = (k+1 <= dm1) ? wexp(lrelu(e1.x + adn.x)) : 0.f;
        float w11 = (k+1 <= dm1) ? wexp(lrelu(e1.y + adn.y)) : 0.f;
        float w20 = (k+2 <= dm1) ? wexp(lrelu(e2.x + adn.x)) : 0.f;
        float w21 = (k+2 <= dm1) ? wexp(lrelu(e2.y + adn.y)) : 0.f;
        float w30 = (k+3 <= dm1) ? wexp(lrelu(e3.x + adn.x)) : 0.f;
        float w31 = (k+3 <= dm1) ? wexp(lrelu(e3.y + adn.y)) : 0.f;
        l0 += (w00 + w10) + (w20 + w30);
        l1 += (w01 + w11) + (w21 + w31);
        float r0x = bf2f(u0.x), r0y = bf2f(u0.y);
        float r1x = bf2f(u1.x), r1y = bf2f(u1.y);
        float r2x = bf2f(u2.x), r2y = bf2f(u2.y);
        float r3x = bf2f(u3.x), r3y = bf2f(u3.y);
        a0x = fmaf(w00, r0x, a0x); a0y = fmaf(w00, r0y, a0y);
        a1x = fmaf(w01, r0x, a1x); a1y = fmaf(w01, r0y, a1y);
        a0x = fmaf(w10, r1x, a0x); a0y = fmaf(w10, r1y, a0y);
        a1x = fmaf(w11, r1x, a1x); a1y = fmaf(w11, r1y, a1y);
        a0x = fmaf(w20, r2x, a0x); a0y = fmaf(w20, r2y, a0y);
        a1x = fmaf(w21, r2x, a1x); a1y = fmaf(w21, r2y, a1y);
        a0x = fmaf(w30, r3x, a0x); a0y = fmaf(w30, r3y, a0y);
        a1x = fmaf(w31, r3x, a1x); a1y = fmaf(w31, r3y, a1y);
    }

    float i0 = 1.f / (l0 + 1e-16f);
    float i1 = 1.f / (l1 + 1e-16f);
    ((ushort2*)(aggx0 + (size_t)n*128))[lane] = make_ushort2(f2bf(a0x*i0), f2bf(a0y*i0));
    ((ushort2*)(aggx1 + (size_t)n*128))[lane] = make_ushort2(f2bf(a1x*i1), f2bf(a1y*i1));
}

// ---------------- bf16 MFMA GEMM ----------------
// C[M x N] = A[M x K] @ BT[N x K]^T, 128x128 tile, BK=32, 4 waves (2x2), 4x4 frags.
// MODE 0 (gemm1): A = (bx ? A1 : A0) per-head aggregate; epilogue bias+ELU, bf16 store.
// MODE 2 (gemm2): plain A0; epilogue stores C and att logits (wx = mu/ls group).
template<int MODE>
__global__ __launch_bounds__(256) void mfma_gemm_k(const unsigned short* __restrict__ A0,
        const unsigned short* __restrict__ A1,
        const unsigned short* __restrict__ BT, unsigned short* __restrict__ C,
        int M, int K, int ldc, const float* __restrict__ bias,
        const float* __restrict__ attS0, const float* __restrict__ attD0,
        const float* __restrict__ attS1, const float* __restrict__ attD1,
        float* __restrict__ outS, float* __restrict__ outD){
    __shared__ unsigned short As[128*40];   // +8 elem pad: 2-way bank conflicts only
    __shared__ unsigned short Bs[128*40];
    int t = threadIdx.x;
    int lane = t & 63, wid = t >> 6;
    int wy = wid >> 1, wx = wid & 1;
    int quad = lane >> 4, l15 = lane & 15;
    int row0 = blockIdx.y * 128;
    int col0 = blockIdx.x * 128;
    const unsigned short* A = (MODE == 0 && blockIdx.x) ? A1 : A0;

    f32x4 acc[4][4];
    #pragma unroll
    for (int i = 0; i < 4; i++)
        #pragma unroll
        for (int j = 0; j < 4; j++)
            acc[i][j] = (f32x4){0.f, 0.f, 0.f, 0.f};

    int r = t >> 2;              // 0..63
    int cofs = (t & 3) * 8;      // elem offset in k-slice

    for (int k0 = 0; k0 < K; k0 += 32){
        int gr0 = min(row0 + r,      M-1);
        int gr1 = min(row0 + r + 64, M-1);
        float4 av0 = *(const float4*)(A  + (size_t)gr0*K + k0 + cofs);
        float4 av1 = *(const float4*)(A  + (size_t)gr1*K + k0 + cofs);
        float4 bv0 = *(const float4*)(BT + (size_t)(col0 + r)*K      + k0 + cofs);
        float4 bv1 = *(const float4*)(BT + (size_t)(col0 + r + 64)*K + k0 + cofs);
        __syncthreads();
        *(float4*)&As[r*40 + cofs]      = av0;
        *(float4*)&As[(r+64)*40 + cofs] = av1;
        *(float4*)&Bs[r*40 + cofs]      = bv0;
        *(float4*)&Bs[(r+64)*40 + cofs] = bv1;
        __syncthreads();

        bf16x8 af[4], bf[4];
        #pragma unroll
        for (int i = 0; i < 4; i++)
            af[i] = *(const bf16x8*)&As[(wy*64 + i*16 + l15)*40 + quad*8];
        #pragma unroll
        for (int j = 0; j < 4; j++)
            bf[j] = *(const bf16x8*)&Bs[(wx*64 + j*16 + l15)*40 + quad*8];
        #pragma unroll
        for (int i = 0; i < 4; i++)
            #pragma unroll
            for (int j = 0; j < 4; j++)
                acc[i][j] = __builtin_amdgcn_mfma_f32_16x16x32_bf16(af[i], bf[j], acc[i][j], 0, 0, 0);
    }

    float aS[4], aD[4], bvals[4];
    #pragma unroll
    for (int j = 0; j < 4; j++){
        int cc = col0 + wx*64 + j*16 + l15;
        if (MODE == 0){
            bvals[j] = bias[cc];
        } else {
            int c2 = j*16 + l15;
            aS[j] = wx ? attS1[c2] : attS0[c2];
            aD[j] = wx ? attD1[c2] : attD0[c2];
        }
    }

    // epilogue: C/D layout col=lane&15, row=quad*4+reg  [m89-verified]
    #pragma unroll
    for (int i = 0; i < 4; i++){
        #pragma unroll
        for (int reg = 0; reg < 4; reg++){
            int rr = row0 + wy*64 + i*16 + quad*4 + reg;
            if (MODE == 0){
                if (rr < M){
                    #pragma unroll
                    for (int j = 0; j < 4; j++){
                        int cc = col0 + wx*64 + j*16 + l15;
                        float v = acc[i][j][reg] + bvals[j];
                        v = v > 0.f ? v : __expf(v) - 1.f;      // ELU
                        C[(size_t)rr*ldc + cc] = f2bf(v);
                    }
                }
            } else {
                float sp = 0.f, dp = 0.f;
                #pragma unroll
                for (int j = 0; j < 4; j++){
                    float v = acc[i][j][reg];
                    int cc = col0 + wx*64 + j*16 + l15;
                    if (rr < M) C[(size_t)rr*ldc + cc] = f2bf(v);
                    sp = fmaf(v, aS[j], sp);
                    dp = fmaf(v, aD[j], dp);
                }
                #pragma unroll
                for (int msk = 1; msk < 16; msk <<= 1){
                    sp += __shfl_xor(sp, msk);
                    dp += __shfl_xor(dp, msk);
                }
                if (l15 == 0 && rr < M){
                    outS[rr*2 + wx] = sp;
                    outD[rr*2 + wx] = dp;
                }
            }
        }
    }
}

// ---------------- conv_mu / conv_ls aggregation (R1-proven): 256B rows ----------------
// 32 threads per node; lane owns 4 channels; g = lane>>4 (0=mu, 1=ls)
__global__ __launch_bounds__(256) void agg2_k(const unsigned short* __restrict__ hml,
        const float* __restrict__ as, const float* __restrict__ ad,
        const int* __restrict__ counts, const int* __restrict__ csr_src,
        const float* __restrict__ b_mu, const float* __restrict__ b_ls,
        float* __restrict__ out){
    int grp = threadIdx.x >> 5, lane = threadIdx.x & 31;
    int n = blockIdx.x*8 + grp;
    if (n >= N_NODES) return;
    int g = lane >> 4;
    const ushort4* hv = (const ushort4*)hml;

    float adh = ad[n*2 + g];
    float ash = as[n*2 + g];

    float w = wexp(lrelu(ash + adh));        // self-loop
    float l = w;
    float4 r = bf4(hv[(size_t)n*32 + lane]);
    float4 acc = make_float4(w*r.x, w*r.y, w*r.z, w*r.w);

    int deg = counts[n];
    int off = n*PAD;
    int dm1 = deg - 1;
    for (int k = 0; k < deg; k += 4){
        int s0 = csr_src[off + k];
        int s1 = csr_src[off + min(k+1, dm1)];
        int s2 = csr_src[off + min(k+2, dm1)];
        int s3 = csr_src[off + min(k+3, dm1)];
        float e0 = as[s0*2 + g], e1 = as[s1*2 + g];
        float e2 = as[s2*2 + g], e3 = as[s3*2 + g];
        float4 r0 = bf4(hv[(size_t)s0*32 + lane]);
        float4 r1 = bf4(hv[(size_t)s1*32 + lane]);
        float4 r2 = bf4(hv[(size_t)s2*32 + lane]);
        float4 r3 = bf4(hv[(size_t)s3*32 + lane]);
        float w0 = wexp(lrelu(e0 + adh));
        float w1 = (k+1 <= dm1) ? wexp(lrelu(e1 + adh)) : 0.f;
        float w2 = (k+2 <= dm1) ? wexp(lrelu(e2 + adh)) : 0.f;
        float w3 = (k+3 <= dm1) ? wexp(lrelu(e3 + adh)) : 0.f;
        l += (w0 + w1) + (w2 + w3);
        acc.x = fmaf(w0, r0.x, acc.x); acc.x = fmaf(w1, r1.x, acc.x);
        acc.x = fmaf(w2, r2.x, acc.x); acc.x = fmaf(w3, r3.x, acc.x);
        acc.y = fmaf(w0, r0.y, acc.y); acc.y = fmaf(w1, r1.y, acc.y);
        acc.y = fmaf(w2, r2.y, acc.y); acc.y = fmaf(w3, r3.y, acc.y);
        acc.z = fmaf(w0, r0.z, acc.z); acc.z = fmaf(w1, r1.z, acc.z);
        acc.z = fmaf(w2, r2.z, acc.z); acc.z = fmaf(w3, r3.z, acc.z);
        acc.w = fmaf(w0, r0.w, acc.w); acc.w = fmaf(w1, r1.w, acc.w);
        acc.w = fmaf(w2, r2.w, acc.w); acc.w = fmaf(w3, r3.w, acc.w);
    }

    float invl = 1.f / (l + 1e-16f);
    int c = (lane & 15) * 4;
    const float* bb = g ? b_ls : b_mu;
    float4 b4 = *(const float4*)&bb[c];
    float4 v;
    v.x = acc.x*invl + b4.x; v.y = acc.y*invl + b4.y;
    v.z = acc.z*invl + b4.z; v.w = acc.w*invl + b4.w;
    float* base = g ? (out + (size_t)N_NODES*64) : out;
    *(float4*)&base[(size_t)n*64 + c] = v;
}

extern "C" void kernel_launch(void* const* d_in, const int* in_sizes, int n_in,
                              void* d_out, int out_size, void* d_ws, size_t ws_size,
                              hipStream_t stream) {
    const float* x           = (const float*)d_in[0];
    const int*   ei          = (const int*)d_in[1];
    const float* W1          = (const float*)d_in[2];
    const float* att_src1    = (const float*)d_in[3];
    const float* att_dst1    = (const float*)d_in[4];
    const float* b1          = (const float*)d_in[5];
    const float* W_mu        = (const float*)d_in[6];
    const float* att_src_mu  = (const float*)d_in[7];
    const float* att_dst_mu  = (const float*)d_in[8];
    const float* b_mu        = (const float*)d_in[9];
    const float* W_ls        = (const float*)d_in[10];
    const float* att_src_ls  = (const float*)d_in[11];
    const float* att_dst_ls  = (const float*)d_in[12];
    const float* b_ls        = (const float*)d_in[13];
    float* out = (float*)d_out;

    const int* srcp = ei;
    const int* dstp = ei + N_EDGES;

    // workspace layout (bf16 stored as unsigned short)
    unsigned short* xb    = (unsigned short*)d_ws;           // [N,128]
    unsigned short* aggx0 = xb    + (size_t)N_NODES*128;     // [N,128] head-0 aggregate
    unsigned short* aggx1 = aggx0 + (size_t)N_NODES*128;     // [N,128] head-1 aggregate
    unsigned short* hbuf  = aggx1 + (size_t)N_NODES*128;     // [N,256] post-ELU h
    unsigned short* hml   = hbuf  + (size_t)N_NODES*256;     // [N,128] = [hm|hl]
    unsigned short* W1T   = hml   + (size_t)N_NODES*128;     // [256,128]
    unsigned short* WmlT  = W1T   + 32768;                   // [128,256]
    int*   counts = (int*)(WmlT + 32768);                    // [N]  (zeroed)
    float2* as1   = (float2*)(counts + N_NODES);             // [N] (s_h0, s_h1)
    float2* ad1   = as1 + N_NODES;                           // [N]
    float*  as2   = (float*)(ad1 + N_NODES);                 // [N,2] (mu, ls)
    float*  ad2   = as2 + 2*N_NODES;                         // [N,2]
    float*  V1    = ad2 + 2*N_NODES;                         // [4][128]
    int*    csr   = (int*)(V1 + 512);                        // [N,PAD]

    // only counts needs zeroing (as1/ad1/as2/ad2 are direct-stored)
    hipMemsetAsync(counts, 0, N_NODES*sizeof(int), stream);

    // V1 = W1 @ att1 (4 x 128)
    vprep_k<<<1, 256, 0, stream>>>(W1, att_src1, att_dst1, V1);

    // prep: x cast + logits1 (rows), W transpose, padded-CSR scatter
    prep_k<<<12500, 256, 0, stream>>>(x, xb, V1, as1, ad1, W1, W_mu, W_ls, W1T, WmlT,
                                      srcp, dstp, counts, csr);

    // layer-1 aggregation in x-space (256B rows, both heads in one pass)
    agg1x_k<<<(N_NODES + 3) / 4, 256, 0, stream>>>(xb, as1, ad1, counts, csr, aggx0, aggx1);

    // gemm1: hbuf[N,256] = ELU([aggx0|aggx1] @ W1T^T + b1)   (bx selects head)
    mfma_gemm_k<0><<<dim3(2, 391), 256, 0, stream>>>(aggx0, aggx1, W1T, hbuf, N_NODES, 128, 256,
                                                     b1, nullptr, nullptr, nullptr, nullptr,
                                                     nullptr, nullptr);

    // gemm2: hml[N,128] = hbuf @ WmlT^T, logits2 fused (wx picks mu/ls group)
    mfma_gemm_k<2><<<dim3(1, 391), 256, 0, stream>>>(hbuf, hbuf, WmlT, hml, N_NODES, 256, 128,
                                                     nullptr, att_src_mu, att_dst_mu,
                                                     att_src_ls, att_dst_ls, as2, ad2);

    // layer-2 aggregation (R1-proven body)
    agg2_k<<<(N_NODES + 7) / 8, 256, 0, stream>>>(hml, as2, ad2, counts, csr, b_mu, b_ls, out);
}